// Round 4
// baseline (13745.872 us; speedup 1.0000x reference)
//
#include <hip/hip_runtime.h>
#include <math.h>

#define N_ROWS 10816   // 64 * 169 rows per timestep
#define T_SEQ 55
#define NPIX 169

__device__ __forceinline__ float sigmoidf_(float x){ return 1.0f/(1.0f+expf(-x)); }

// ---------------------------------------------------------------------------
// Kernel 1: fused input transpose + 4x (1x1 conv + ReLU) chain.
// Writes channel-major: out[(l*30+co)*N_ROWS + n], n = b*169+p.
// ---------------------------------------------------------------------------
__global__ __launch_bounds__(256) void conv1x1_chain(
    const float* __restrict__ x,
    const float* __restrict__ w0, const float* __restrict__ b0,
    const float* __restrict__ w1, const float* __restrict__ b1,
    const float* __restrict__ w2, const float* __restrict__ b2,
    const float* __restrict__ w3, const float* __restrict__ b3,
    float* __restrict__ out)
{
    int n = blockIdx.x*256 + threadIdx.x;
    int l = blockIdx.y;
    if (n >= N_ROWS) return;
    const float* xp = x + ((size_t)n*T_SEQ + l)*24;
    float in24[24];
    #pragma unroll
    for (int i=0;i<6;i++){
        float4 v = *(const float4*)(xp + 4*i);
        in24[4*i]=v.x; in24[4*i+1]=v.y; in24[4*i+2]=v.z; in24[4*i+3]=v.w;
    }
    float a[30], c[30];
    #pragma unroll
    for (int co=0;co<30;co++) a[co]=b0[co];
    #pragma unroll
    for (int ci=0;ci<24;ci++){
        float v = in24[ci];
        #pragma unroll
        for (int co=0;co<30;co++) a[co] = fmaf(v, w0[ci*30+co], a[co]);
    }
    #pragma unroll
    for (int co=0;co<30;co++) a[co] = fmaxf(a[co],0.f);

#define LAYER30(wp, bp) \
    { _Pragma("unroll") for (int co=0;co<30;co++) c[co]=(bp)[co]; \
      _Pragma("unroll") for (int ci=0;ci<30;ci++){ float v=a[ci]; \
        _Pragma("unroll") for (int co=0;co<30;co++) c[co]=fmaf(v,(wp)[ci*30+co],c[co]); } \
      _Pragma("unroll") for (int co=0;co<30;co++) a[co]=fmaxf(c[co],0.f); }

    LAYER30(w1,b1);
    LAYER30(w2,b2);
    LAYER30(w3,b3);
#undef LAYER30

    float* op = out + (size_t)l*30*N_ROWS + n;
    #pragma unroll
    for (int co=0;co<30;co++) op[(size_t)co*N_ROWS] = a[co];
}

// ---------------------------------------------------------------------------
// Kernel 2: 5x5 SAME conv + ReLU, channel-major, IN-PLACE, TWO-PHASE staging.
// (unchanged from R3: 17.3 KB LDS -> 51% occupancy, 380 us/dispatch)
// ---------------------------------------------------------------------------
__global__ __launch_bounds__(192) void conv5x5(
    float* __restrict__ buf, const float* __restrict__ w,
    const float* __restrict__ bias)
{
    __shared__ float img[15*289];
    int bi = blockIdx.x;
    int l = bi >> 6;
    int b = bi & 63;
    float* ip = buf + (size_t)l*30*N_ROWS + (size_t)b*NPIX;
    int tid = threadIdx.x;

    int p = tid;
    bool act = p < 169;
    int pc = act ? p : 0;
    int y = pc/13, x0 = pc - y*13;

    float acc[30];
    #pragma unroll
    for (int co=0;co<30;co++) acc[co]=bias[co];

    for (int i = tid; i < 15*289; i += 192) img[i] = 0.f;

    for (int half = 0; half < 2; half++){
        __syncthreads();
        for (int i = tid; i < 15*169; i += 192){
            int ci = i/169, pp = i - ci*169;
            int yy = pp/13, xx = pp - yy*13;
            img[ci*289 + (yy+2)*17 + (xx+2)] =
                ip[(size_t)(half*15 + ci)*N_ROWS + pp];
        }
        __syncthreads();
        for (int dy=0; dy<5; dy++){
          for (int dx=0; dx<5; dx++){
            const float* wp = w + (size_t)((dy*5+dx)*30 + half*15)*30;
            const float* im = img + (y+dy)*17 + (x0+dx);
            #pragma unroll
            for (int ci=0; ci<15; ci++){
              float v = im[ci*289];
              #pragma unroll
              for (int co=0;co<30;co++) acc[co] = fmaf(v, wp[ci*30+co], acc[co]);
            }
          }
        }
    }
    if (act){
      #pragma unroll
      for (int co=0;co<30;co++) ip[(size_t)co*N_ROWS + p] = fmaxf(acc[co],0.f);
    }
}

// ---------------------------------------------------------------------------
// Kernel 3: weight repack for the persistent LSTM.
// W[k][col], col = g*100 + cg*5 + j  ->  P[k][cg][g*5+j]  (20 floats per
// (k,cg), 16B aligned). Biases likewise to [cg][20].
// ---------------------------------------------------------------------------
__global__ __launch_bounds__(256) void repack_w(
    const float* __restrict__ l1w, const float* __restrict__ l1b,
    const float* __restrict__ l2w, const float* __restrict__ l2b,
    float* __restrict__ p1, float* __restrict__ pb1,
    float* __restrict__ p2, float* __restrict__ pb2)
{
    int i = blockIdx.x*256 + threadIdx.x;
    if (i < 52000){
        int k=i/400, col=i-k*400; int g=col/100, cc=col-g*100; int cg=cc/5, j=cc-cg*5;
        p1[k*400 + cg*20 + g*5 + j] = l1w[i];
    } else if (i < 132000){
        int ii=i-52000; int k=ii/400, col=ii-k*400; int g=col/100, cc=col-g*100; int cg=cc/5, j=cc-cg*5;
        p2[k*400 + cg*20 + g*5 + j] = l2w[ii];
    } else if (i < 132400){
        int col=i-132000; int g=col/100, cc=col-g*100; int cg=cc/5, j=cc-cg*5;
        pb1[cg*20 + g*5 + j] = l1b[col];
    } else if (i < 132800){
        int col=i-132400; int g=col/100, cc=col-g*100; int cg=cc/5, j=cc-cg*5;
        pb2[cg*20 + g*5 + j] = l2b[col];
    }
}

// ---------------------------------------------------------------------------
// Kernel 4: PERSISTENT fused 2-layer LSTM + final projection.
// LSTM rows are independent (recurrence only over t), so each block owns 16
// rows and runs all 55 timesteps of both layers internally: c in registers,
// h in LDS double-buffers, weights streamed from L1/L2 (packed layout).
// Thread = (row r = tid/20, colgroup cg = tid%20) -> 5 base cols x 4 gates.
// Grid 676 x 320 threads = 13.2 waves/CU. Replaces 110 launches with 1.
// ---------------------------------------------------------------------------
__global__ __launch_bounds__(320, 3) void lstm_persist(
    const float* __restrict__ xall,   // [55][30][N] conv output
    const float* __restrict__ p1, const float* __restrict__ pb1,
    const float* __restrict__ p2, const float* __restrict__ pb2,
    const float* __restrict__ we, const float* __restrict__ be,
    float* __restrict__ out)          // [N][55]
{
    __shared__ float x_lds[30*16];    // [k][r]
    __shared__ float h1[2][16*100];   // [r][col] double buffer
    __shared__ float h2[2][16*100];

    int tid = threadIdx.x;
    int r  = tid/20;
    int cg = tid - r*20;
    int n0 = blockIdx.x*16;

    for (int i=tid; i<1600; i+=320){ h1[0][i]=0.f; h2[0][i]=0.f; }
    float c1[5]={0,0,0,0,0}, c2[5]={0,0,0,0,0};

    const float* w1 = p1 + cg*20;
    const float* w2 = p2 + cg*20;
    const float* bb1 = pb1 + cg*20;
    const float* bb2 = pb2 + cg*20;

    float acc[20];

#define FMA20(WROW, A) { \
    float a_ = (A); const float* wp_ = (WROW); \
    _Pragma("unroll") for (int t4=0;t4<5;t4++){ \
        float4 w_ = *(const float4*)(wp_ + 4*t4); \
        acc[4*t4  ] = fmaf(a_, w_.x, acc[4*t4  ]); \
        acc[4*t4+1] = fmaf(a_, w_.y, acc[4*t4+1]); \
        acc[4*t4+2] = fmaf(a_, w_.z, acc[4*t4+2]); \
        acc[4*t4+3] = fmaf(a_, w_.w, acc[4*t4+3]); } }

    int cur = 0;
    for (int t=0; t<T_SEQ; t++){
        // stage x_t for this block's 16 rows (coalesced: r fastest)
        for (int i=tid; i<480; i+=320){
            int rr = i & 15, k = i >> 4;
            x_lds[i] = xall[((size_t)t*30 + k)*N_ROWS + n0 + rr];
        }
        __syncthreads();

        // ---- layer 1: z = [x_t, h1] @ W1 + b1
        #pragma unroll
        for (int t4=0;t4<5;t4++){
            float4 v = *(const float4*)(bb1 + 4*t4);
            acc[4*t4]=v.x; acc[4*t4+1]=v.y; acc[4*t4+2]=v.z; acc[4*t4+3]=v.w;
        }
        #pragma unroll 2
        for (int k=0; k<30; k++)  FMA20(w1 + (size_t)k*400, x_lds[k*16 + r]);
        {
            const float* hc = h1[cur] + r*100;
            #pragma unroll 2
            for (int k=0; k<100; k++) FMA20(w1 + (size_t)(30+k)*400, hc[k]);
        }
        int nxt = cur ^ 1;
        #pragma unroll
        for (int j=0;j<5;j++){
            float gi = sigmoidf_(acc[j]);
            float gj = tanhf(acc[5+j]);
            float gf = sigmoidf_(acc[10+j] + 1.0f);
            float go = sigmoidf_(acc[15+j]);
            float cn = gf*c1[j] + gi*gj;
            c1[j] = cn;
            h1[nxt][r*100 + cg*5 + j] = go * tanhf(cn);
        }
        __syncthreads();

        // ---- layer 2: z = [h1_new, h2] @ W2 + b2
        #pragma unroll
        for (int t4=0;t4<5;t4++){
            float4 v = *(const float4*)(bb2 + 4*t4);
            acc[4*t4]=v.x; acc[4*t4+1]=v.y; acc[4*t4+2]=v.z; acc[4*t4+3]=v.w;
        }
        {
            const float* xa = h1[nxt] + r*100;
            #pragma unroll 2
            for (int k=0; k<100; k++) FMA20(w2 + (size_t)k*400, xa[k]);
            const float* ha = h2[cur] + r*100;
            #pragma unroll 2
            for (int k=0; k<100; k++) FMA20(w2 + (size_t)(100+k)*400, ha[k]);
        }
        #pragma unroll
        for (int j=0;j<5;j++){
            float gi = sigmoidf_(acc[j]);
            float gj = tanhf(acc[5+j]);
            float gf = sigmoidf_(acc[10+j] + 1.0f);
            float go = sigmoidf_(acc[15+j]);
            float cn = gf*c2[j] + gi*gj;
            c2[j] = cn;
            h2[nxt][r*100 + cg*5 + j] = go * tanhf(cn);
        }
        __syncthreads();

        // ---- final 1x1 projection for this timestep (16 threads, overlaps
        // with other waves' next-step x staging)
        if (tid < 16){
            float s = be[0];
            const float* hp = h2[nxt] + tid*100;
            #pragma unroll 4
            for (int col=0; col<100; col++) s = fmaf(hp[col], we[col], s);
            out[(size_t)(n0+tid)*T_SEQ + t] = s;
        }
        cur = nxt;
    }
#undef FMA20
}

// ---------------------------------------------------------------------------
extern "C" void kernel_launch(void* const* d_in, const int* in_sizes, int n_in,
                              void* d_out, int out_size, void* d_ws, size_t ws_size,
                              hipStream_t stream)
{
    const float* x    = (const float*)d_in[0];
    const float* w10  = (const float*)d_in[1];  const float* b10 = (const float*)d_in[2];
    const float* w11  = (const float*)d_in[3];  const float* b11 = (const float*)d_in[4];
    const float* w12  = (const float*)d_in[5];  const float* b12 = (const float*)d_in[6];
    const float* w13  = (const float*)d_in[7];  const float* b13 = (const float*)d_in[8];
    const float* w20  = (const float*)d_in[9];  const float* b20 = (const float*)d_in[10];
    const float* w21  = (const float*)d_in[11]; const float* b21 = (const float*)d_in[12];
    const float* w22  = (const float*)d_in[13]; const float* b22 = (const float*)d_in[14];
    const float* w23  = (const float*)d_in[15]; const float* b23 = (const float*)d_in[16];
    const float* l1w  = (const float*)d_in[17]; const float* l1b = (const float*)d_in[18];
    const float* l2w  = (const float*)d_in[19]; const float* l2b = (const float*)d_in[20];
    const float* we   = (const float*)d_in[21]; const float* be  = (const float*)d_in[22];
    float* out = (float*)d_out;

    // workspace: conv slab (in-place 5x5) + packed weights = ~72 MB
    const size_t NF = (size_t)30*N_ROWS;
    float* buf0 = (float*)d_ws;                    // [55][30][N]
    float* p1   = buf0 + (size_t)T_SEQ*NF;         // [130][20][20]
    float* pb1  = p1 + 52000;                      // [20][20]
    float* p2   = pb1 + 400;                       // [200][20][20]
    float* pb2  = p2 + 80000;                      // [20][20]

    repack_w<<<(132800+255)/256, 256, 0, stream>>>(l1w, l1b, l2w, l2b,
                                                   p1, pb1, p2, pb2);

    dim3 g1((N_ROWS+255)/256, T_SEQ);
    conv1x1_chain<<<g1, 256, 0, stream>>>(x, w10,b10, w11,b11, w12,b12, w13,b13, buf0);
    conv5x5<<<T_SEQ*64, 192, 0, stream>>>(buf0, w20, b20);
    conv5x5<<<T_SEQ*64, 192, 0, stream>>>(buf0, w21, b21);
    conv5x5<<<T_SEQ*64, 192, 0, stream>>>(buf0, w22, b22);
    conv5x5<<<T_SEQ*64, 192, 0, stream>>>(buf0, w23, b23);

    lstm_persist<<<N_ROWS/16, 320, 0, stream>>>(buf0, p1, pb1, p2, pb2,
                                                we, be, out);
}

// Round 5
// 5490.258 us; speedup vs baseline: 2.5037x; 2.5037x over previous
//
#include <hip/hip_runtime.h>
#include <math.h>

#define N_ROWS 10816   // 64 * 169 rows per timestep
#define T_SEQ 55
#define NPIX 169

__device__ __forceinline__ float sigmoidf_(float x){ return 1.0f/(1.0f+expf(-x)); }

// ---------------------------------------------------------------------------
// Kernel 1: fused input transpose + 4x (1x1 conv + ReLU) chain. (unchanged)
// Writes channel-major: out[(l*30+co)*N_ROWS + n], n = b*169+p.
// ---------------------------------------------------------------------------
__global__ __launch_bounds__(256) void conv1x1_chain(
    const float* __restrict__ x,
    const float* __restrict__ w0, const float* __restrict__ b0,
    const float* __restrict__ w1, const float* __restrict__ b1,
    const float* __restrict__ w2, const float* __restrict__ b2,
    const float* __restrict__ w3, const float* __restrict__ b3,
    float* __restrict__ out)
{
    int n = blockIdx.x*256 + threadIdx.x;
    int l = blockIdx.y;
    if (n >= N_ROWS) return;
    const float* xp = x + ((size_t)n*T_SEQ + l)*24;
    float in24[24];
    #pragma unroll
    for (int i=0;i<6;i++){
        float4 v = *(const float4*)(xp + 4*i);
        in24[4*i]=v.x; in24[4*i+1]=v.y; in24[4*i+2]=v.z; in24[4*i+3]=v.w;
    }
    float a[30], c[30];
    #pragma unroll
    for (int co=0;co<30;co++) a[co]=b0[co];
    #pragma unroll
    for (int ci=0;ci<24;ci++){
        float v = in24[ci];
        #pragma unroll
        for (int co=0;co<30;co++) a[co] = fmaf(v, w0[ci*30+co], a[co]);
    }
    #pragma unroll
    for (int co=0;co<30;co++) a[co] = fmaxf(a[co],0.f);

#define LAYER30(wp, bp) \
    { _Pragma("unroll") for (int co=0;co<30;co++) c[co]=(bp)[co]; \
      _Pragma("unroll") for (int ci=0;ci<30;ci++){ float v=a[ci]; \
        _Pragma("unroll") for (int co=0;co<30;co++) c[co]=fmaf(v,(wp)[ci*30+co],c[co]); } \
      _Pragma("unroll") for (int co=0;co<30;co++) a[co]=fmaxf(c[co],0.f); }

    LAYER30(w1,b1);
    LAYER30(w2,b2);
    LAYER30(w3,b3);
#undef LAYER30

    float* op = out + (size_t)l*30*N_ROWS + n;
    #pragma unroll
    for (int co=0;co<30;co++) op[(size_t)co*N_ROWS] = a[co];
}

// ---------------------------------------------------------------------------
// Kernel 2: 5x5 SAME conv + ReLU, channel-major, IN-PLACE, TWO-PHASE staging.
// (unchanged from R3: 17.3 KB LDS -> 51% occupancy, ~380 us/dispatch)
// ---------------------------------------------------------------------------
__global__ __launch_bounds__(192) void conv5x5(
    float* __restrict__ buf, const float* __restrict__ w,
    const float* __restrict__ bias)
{
    __shared__ float img[15*289];
    int bi = blockIdx.x;
    int l = bi >> 6;
    int b = bi & 63;
    float* ip = buf + (size_t)l*30*N_ROWS + (size_t)b*NPIX;
    int tid = threadIdx.x;

    int p = tid;
    bool act = p < 169;
    int pc = act ? p : 0;
    int y = pc/13, x0 = pc - y*13;

    float acc[30];
    #pragma unroll
    for (int co=0;co<30;co++) acc[co]=bias[co];

    for (int i = tid; i < 15*289; i += 192) img[i] = 0.f;

    for (int half = 0; half < 2; half++){
        __syncthreads();
        for (int i = tid; i < 15*169; i += 192){
            int ci = i/169, pp = i - ci*169;
            int yy = pp/13, xx = pp - yy*13;
            img[ci*289 + (yy+2)*17 + (xx+2)] =
                ip[(size_t)(half*15 + ci)*N_ROWS + pp];
        }
        __syncthreads();
        for (int dy=0; dy<5; dy++){
          for (int dx=0; dx<5; dx++){
            const float* wp = w + (size_t)((dy*5+dx)*30 + half*15)*30;
            const float* im = img + (y+dy)*17 + (x0+dx);
            #pragma unroll
            for (int ci=0; ci<15; ci++){
              float v = im[ci*289];
              #pragma unroll
              for (int co=0;co<30;co++) acc[co] = fmaf(v, wp[ci*30+co], acc[co]);
            }
          }
        }
    }
    if (act){
      #pragma unroll
      for (int co=0;co<30;co++) ip[(size_t)co*N_ROWS + p] = fmaxf(acc[co],0.f);
    }
}

// ---------------------------------------------------------------------------
// Kernel 3: weight repack. pc = c*4 + g (c in [0,128) zero-padded, g in
// [0,4)), row-major [k][512]. A wave reading pc = wavebase + lane*2 gets a
// fully COALESCED 512 B load per k (this is the fix for R4's scatter-gather
// VMEM death). Biases packed the same way.
// ---------------------------------------------------------------------------
__global__ __launch_bounds__(256) void repack_w2(
    const float* __restrict__ l1w, const float* __restrict__ l1b,
    const float* __restrict__ l2w, const float* __restrict__ l2b,
    float* __restrict__ pw1, float* __restrict__ pb1,
    float* __restrict__ pw2, float* __restrict__ pb2)
{
    const int T1 = 130*512, T2 = 200*512;
    int i = blockIdx.x*256 + threadIdx.x;
    if (i < T1){
        int k = i >> 9, pc = i & 511, c = pc >> 2, g = pc & 3;
        pw1[i] = (c < 100) ? l1w[(size_t)k*400 + g*100 + c] : 0.f;
    } else if (i < T1 + T2){
        int ii = i - T1;
        int k = ii >> 9, pc = ii & 511, c = pc >> 2, g = pc & 3;
        pw2[ii] = (c < 100) ? l2w[(size_t)k*400 + g*100 + c] : 0.f;
    } else if (i < T1 + T2 + 512){
        int pc = i - T1 - T2, c = pc >> 2, g = pc & 3;
        pb1[pc] = (c < 100) ? l1b[g*100 + c] : 0.f;
    } else if (i < T1 + T2 + 1024){
        int pc = i - T1 - T2 - 512, c = pc >> 2, g = pc & 3;
        pb2[pc] = (c < 100) ? l2b[g*100 + c] : 0.f;
    }
}

// ---------------------------------------------------------------------------
// Kernel 4: PERSISTENT fused 2-layer LSTM + projection, v2.
// Block = 16 rows x 512 packed cols, 4 waves; wave w owns cols
// [w*128, w*128+128) (disjoint -> no duplicated weight stream). Lane owns
// 2 adjacent packed cols x 16 rows = 32 accs. Per k: ONE coalesced float2
// weight load from L2 + 4 broadcast ds_read_b128 for activations + 32 FMA.
// Even lane holds gates (i,j), odd lane (f,o) of the same cell c; the gate
// update pairs them via __shfl_xor(1) and both lanes redundantly keep the
// c-state. h lives in LDS double buffers; x staged per step; final 1x1
// projection fused. Grid 676 x 256.
// ---------------------------------------------------------------------------
__global__ __launch_bounds__(256) void lstm_persist2(
    const float* __restrict__ xall,   // [55][30][N]
    const float* __restrict__ pw1, const float* __restrict__ pb1,
    const float* __restrict__ pw2, const float* __restrict__ pb2,
    const float* __restrict__ we,  const float* __restrict__ be,
    float* __restrict__ out)          // [N][55]
{
    __shared__ float xs[30*16];       // [k][r]
    __shared__ float h1[2][100*16];   // [c][r] double buffer
    __shared__ float h2[2][100*16];
    __shared__ float pbuf[128];

    const int tid  = threadIdx.x;
    const int wave = tid >> 6;
    const int lane = tid & 63;
    const int n0   = blockIdx.x * 16;
    const int pc0  = wave*128 + lane*2;   // my 2 packed cols
    const int c    = pc0 >> 2;            // my cell index (0..127)
    const int codd = lane & 1;             // 0: gates (i,j); 1: gates (f,o)
    const bool cvalid = (c < 100);

    for (int i=tid; i<1600; i+=256){ h1[0][i]=0.f; h2[0][i]=0.f; }

    float cs1[16], cs2[16];
    #pragma unroll
    for (int r=0;r<16;r++){ cs1[r]=0.f; cs2[r]=0.f; }

    const float2 b1v = *(const float2*)(pb1 + pc0);
    const float2 b2v = *(const float2*)(pb2 + pc0);

    __syncthreads();

    float accA[16], accB[16], hreg[16];

#define GK(PW, ACT, KBASE, KLEN) \
    { _Pragma("unroll 2") \
      for (int k=0; k<(KLEN); k++){ \
        float2 wv = *(const float2*)((PW) + (size_t)((KBASE)+k)*512 + pc0); \
        const float4* ap = (const float4*)((ACT) + k*16); \
        float av[16]; \
        *(float4*)(av+0)=ap[0]; *(float4*)(av+4)=ap[1]; \
        *(float4*)(av+8)=ap[2]; *(float4*)(av+12)=ap[3]; \
        _Pragma("unroll") \
        for (int r=0;r<16;r++){ \
            accA[r]=fmaf(av[r],wv.x,accA[r]); \
            accB[r]=fmaf(av[r],wv.y,accB[r]); } } }

#define EPI(CS, HDST) \
    { _Pragma("unroll") \
      for (int r=0;r<16;r++){ \
        float za = accA[r], zb = accB[r]; \
        float oa = __shfl_xor(za, 1, 64); \
        float ob = __shfl_xor(zb, 1, 64); \
        float zi = codd ? oa : za; \
        float zj = codd ? ob : zb; \
        float zf = codd ? za : oa; \
        float zo = codd ? zb : ob; \
        float gi = sigmoidf_(zi); \
        float gj = tanhf(zj); \
        float gf = sigmoidf_(zf + 1.0f); \
        float go = sigmoidf_(zo); \
        float cn = gf*(CS)[r] + gi*gj; \
        (CS)[r] = cn; \
        hreg[r] = go * tanhf(cn); } \
      if (cvalid && !codd){ \
        float4* hp = (float4*)((HDST) + c*16); \
        hp[0] = *(float4*)(hreg+0);  hp[1] = *(float4*)(hreg+4); \
        hp[2] = *(float4*)(hreg+8);  hp[3] = *(float4*)(hreg+12); } }

    int cur = 0;
    for (int t=0; t<T_SEQ; t++){
        // stage x_t for this block's 16 rows (coalesced float4)
        if (tid < 120){
            int k = tid >> 2, q = tid & 3;
            float4 v = *(const float4*)(xall + ((size_t)t*30 + k)*N_ROWS + n0 + q*4);
            *(float4*)(xs + k*16 + q*4) = v;
        }
        __syncthreads();
        int nxt = cur ^ 1;

        // ---- layer 1: z = [x_t, h1] @ W1 + b1
        #pragma unroll
        for (int r=0;r<16;r++){ accA[r]=b1v.x; accB[r]=b1v.y; }
        GK(pw1, xs,      0,  30);
        GK(pw1, h1[cur], 30, 100);
        EPI(cs1, h1[nxt]);
        __syncthreads();

        // ---- layer 2: z = [h1_new, h2] @ W2 + b2
        #pragma unroll
        for (int r=0;r<16;r++){ accA[r]=b2v.x; accB[r]=b2v.y; }
        GK(pw2, h1[nxt], 0,   100);
        GK(pw2, h2[cur], 100, 100);
        EPI(cs2, h2[nxt]);
        __syncthreads();

        // ---- fused 1x1 projection: out[n][t] = h2_new . we + be
        if (tid < 128){
            int r = tid & 15, s = tid >> 4;          // s in [0,8)
            int cb = s*13, ce = (s==7) ? 100 : cb+13;
            float pth = 0.f;
            for (int cc=cb; cc<ce; cc++)
                pth = fmaf(h2[nxt][cc*16 + r], we[cc], pth);
            pbuf[tid] = pth;
        }
        __syncthreads();
        if (tid < 16){
            float s = be[0];
            #pragma unroll
            for (int q=0;q<8;q++) s += pbuf[q*16 + tid];
            out[(size_t)(n0+tid)*T_SEQ + t] = s;
        }
        cur = nxt;
    }
#undef GK
#undef EPI
}

// ---------------------------------------------------------------------------
extern "C" void kernel_launch(void* const* d_in, const int* in_sizes, int n_in,
                              void* d_out, int out_size, void* d_ws, size_t ws_size,
                              hipStream_t stream)
{
    const float* x    = (const float*)d_in[0];
    const float* w10  = (const float*)d_in[1];  const float* b10 = (const float*)d_in[2];
    const float* w11  = (const float*)d_in[3];  const float* b11 = (const float*)d_in[4];
    const float* w12  = (const float*)d_in[5];  const float* b12 = (const float*)d_in[6];
    const float* w13  = (const float*)d_in[7];  const float* b13 = (const float*)d_in[8];
    const float* w20  = (const float*)d_in[9];  const float* b20 = (const float*)d_in[10];
    const float* w21  = (const float*)d_in[11]; const float* b21 = (const float*)d_in[12];
    const float* w22  = (const float*)d_in[13]; const float* b22 = (const float*)d_in[14];
    const float* w23  = (const float*)d_in[15]; const float* b23 = (const float*)d_in[16];
    const float* l1w  = (const float*)d_in[17]; const float* l1b = (const float*)d_in[18];
    const float* l2w  = (const float*)d_in[19]; const float* l2b = (const float*)d_in[20];
    const float* we   = (const float*)d_in[21]; const float* be  = (const float*)d_in[22];
    float* out = (float*)d_out;

    // workspace: conv slab 71.4 MB + packed weights ~0.7 MB
    const size_t NF = (size_t)30*N_ROWS;
    float* buf0 = (float*)d_ws;                    // [55][30][N]
    float* pw1  = buf0 + (size_t)T_SEQ*NF;         // [130][512]
    float* pw2  = pw1 + 130*512;                   // [200][512]
    float* pb1  = pw2 + 200*512;                   // [512]
    float* pb2  = pb1 + 512;                       // [512]

    repack_w2<<<(130*512+200*512+1024+255)/256, 256, 0, stream>>>(
        l1w, l1b, l2w, l2b, pw1, pb1, pw2, pb2);

    dim3 g1((N_ROWS+255)/256, T_SEQ);
    conv1x1_chain<<<g1, 256, 0, stream>>>(x, w10,b10, w11,b11, w12,b12, w13,b13, buf0);
    conv5x5<<<T_SEQ*64, 192, 0, stream>>>(buf0, w20, b20);
    conv5x5<<<T_SEQ*64, 192, 0, stream>>>(buf0, w21, b21);
    conv5x5<<<T_SEQ*64, 192, 0, stream>>>(buf0, w22, b22);
    conv5x5<<<T_SEQ*64, 192, 0, stream>>>(buf0, w23, b23);

    lstm_persist2<<<N_ROWS/16, 256, 0, stream>>>(buf0, pw1, pb1, pw2, pb2,
                                                 we, be, out);
}